// Round 1
// baseline (1845.266 us; speedup 1.0000x reference)
//
#include <hip/hip_runtime.h>
#include <hip/hip_bf16.h>

#define N_NODES 100000
#define N_EDGES 3200000
#define IN_F 128
#define OUT_F 64
#define HEADS 8
#define ALPHA 0.2f

typedef __bf16 bf16x8 __attribute__((ext_vector_type(8)));
typedef float f32x4 __attribute__((ext_vector_type(4)));
typedef __attribute__((ext_vector_type(8))) unsigned short ushort8;

static __device__ __forceinline__ unsigned short f2b(float f) {
    __hip_bfloat16 h = __float2bfloat16(f);
    return __builtin_bit_cast(unsigned short, h);
}
static __device__ __forceinline__ float b2f(unsigned short u) {
    unsigned int x = ((unsigned int)u) << 16;
    return __builtin_bit_cast(float, x);
}

// ---------------- W transpose+convert: Wt[c=h*64+f][k] bf16 ----------------
__global__ void k_prep_w(const float* __restrict__ W, unsigned short* __restrict__ Wt) {
    int idx = blockIdx.x * 256 + threadIdx.x;   // = c*128 + k, total 65536
    if (idx >= HEADS * OUT_F * IN_F) return;
    int k = idx & 127;
    int c = idx >> 7;
    int h = c >> 6;
    int f = c & 63;
    Wt[idx] = f2b(W[h * IN_F * OUT_F + k * OUT_F + f]);
}

// ---------------- u[h][k] = sum_f W[h][k][f]*a[h][f]; v with a[h][64+f] ----
__global__ __launch_bounds__(1024) void k_uv(const float* __restrict__ W,
                                             const float* __restrict__ a,
                                             float* __restrict__ u, float* __restrict__ v) {
    int t = threadIdx.x;          // 1024 = 8 heads * 128 k
    int h = t >> 7, k = t & 127;
    const float* Wrow = W + h * IN_F * OUT_F + k * OUT_F;
    const float* ah = a + h * 2 * OUT_F;
    float su = 0.f, sv = 0.f;
    for (int f = 0; f < OUT_F; ++f) {
        float wv = Wrow[f];
        su += wv * ah[f];
        sv += wv * ah[OUT_F + f];
    }
    u[t] = su;
    v[t] = sv;
}

// ---------------- GEMM: Wh[n][512] bf16 = x[n][128] @ Wt^T -----------------
// block: 256 thr (4 waves); tile 64 rows x 512 cols (4 groups of 128 cols)
#define LDK 136   // padded K stride (bf16 elems): 272 B -> bank-conflict-free frags
__global__ __launch_bounds__(256) void k_gemm(const float* __restrict__ x,
                                              const unsigned short* __restrict__ Wt,
                                              unsigned short* __restrict__ Wh) {
    __shared__ unsigned short Al[64 * LDK];
    __shared__ unsigned short Bl[128 * LDK];
    const int tid = threadIdx.x;
    const int tile0 = blockIdx.x * 64;
    // stage A (x tile, fp32 -> bf16): 64 rows x 128 k
    for (int it = 0; it < 8; ++it) {
        int idx = tid + it * 256;            // 0..2047 float4s
        int r = idx >> 5;
        int k4 = (idx & 31) << 2;
        int gr = tile0 + r;
        if (gr >= N_NODES) gr = N_NODES - 1;
        const float4 xv = *reinterpret_cast<const float4*>(x + (size_t)gr * IN_F + k4);
        ushort4 pv = make_ushort4(f2b(xv.x), f2b(xv.y), f2b(xv.z), f2b(xv.w));
        *reinterpret_cast<ushort4*>(&Al[r * LDK + k4]) = pv;
    }
    const int lane = tid & 63, wid = tid >> 6;
    const int wr = wid >> 1, wc = wid & 1;   // wave tile: rows wr*32, cols wc*64
    const int l15 = lane & 15, lq = lane >> 4;

    for (int g = 0; g < 4; ++g) {
        __syncthreads();   // prev compute/epilogue done (also covers A staging at g=0)
        // stage B: global cols g*128 .. g*128+127, layout Bl[c][k]
        for (int it = 0; it < 8; ++it) {
            int idx = tid + it * 256;        // 0..2047 vec8s
            int c = idx >> 4;
            int k8 = (idx & 15) << 3;
            *reinterpret_cast<ushort8*>(&Bl[c * LDK + k8]) =
                *reinterpret_cast<const ushort8*>(Wt + (size_t)(g * 128 + c) * IN_F + k8);
        }
        __syncthreads();

        f32x4 acc[2][4] = {};
        for (int ks = 0; ks < 4; ++ks) {
            int koff = ks * 32 + lq * 8;
            bf16x8 af[2], bfr[4];
            for (int m = 0; m < 2; ++m)
                af[m] = *reinterpret_cast<const bf16x8*>(&Al[(wr * 32 + m * 16 + l15) * LDK + koff]);
            for (int n = 0; n < 4; ++n)
                bfr[n] = *reinterpret_cast<const bf16x8*>(&Bl[(wc * 64 + n * 16 + l15) * LDK + koff]);
            for (int m = 0; m < 2; ++m)
                for (int n = 0; n < 4; ++n)
                    acc[m][n] = __builtin_amdgcn_mfma_f32_16x16x32_bf16(af[m], bfr[n], acc[m][n], 0, 0, 0);
        }
        // epilogue: D col = lane&15, row = (lane>>4)*4 + reg
        for (int m = 0; m < 2; ++m)
            for (int n = 0; n < 4; ++n) {
                int row0 = tile0 + wr * 32 + m * 16 + lq * 4;
                int colg = g * 128 + wc * 64 + n * 16 + l15;
                for (int r2 = 0; r2 < 4; ++r2) {
                    int rr = row0 + r2;
                    if (rr < N_NODES)
                        Wh[(size_t)rr * 512 + colg] = f2b(acc[m][n][r2]);
                }
            }
    }
}

// ---------------- logits: asrc[n][h] = x[n]·u[h], atgt[n][h] = x[n]·v[h] ---
__global__ __launch_bounds__(256) void k_adot(const float* __restrict__ x,
                                              const float* __restrict__ u,
                                              const float* __restrict__ v,
                                              float* __restrict__ asrc,
                                              float* __restrict__ atgt) {
    int node = (blockIdx.x * 256 + threadIdx.x) >> 6;
    int lane = threadIdx.x & 63;
    if (node >= N_NODES) return;
    float xa = x[(size_t)node * 128 + lane];
    float xb = x[(size_t)node * 128 + 64 + lane];
    for (int h = 0; h < 8; ++h) {
        float s1 = xa * u[h * 128 + lane] + xb * u[h * 128 + 64 + lane];
        float s2 = xa * v[h * 128 + lane] + xb * v[h * 128 + 64 + lane];
        for (int d = 1; d < 64; d <<= 1) {
            s1 += __shfl_xor(s1, d);
            s2 += __shfl_xor(s2, d);
        }
        if (lane == 0) {
            asrc[node * 8 + h] = s1;
            atgt[node * 8 + h] = s2;
        }
    }
}

// ---------------- histogram over src --------------------------------------
__global__ void k_hist(const int* __restrict__ src, int* __restrict__ count) {
    int i = blockIdx.x * 256 + threadIdx.x;
    int stride = gridDim.x * 256;
    for (; i < N_EDGES; i += stride) atomicAdd(&count[src[i]], 1);
}

// ---------------- 3-kernel exclusive scan ---------------------------------
__global__ __launch_bounds__(256) void k_scan1(const int* __restrict__ count,
                                               int* __restrict__ rowptr,
                                               int* __restrict__ bsum) {
    __shared__ int s[256];
    int t = threadIdx.x;
    int i = blockIdx.x * 256 + t;
    int vv = (i < N_NODES) ? count[i] : 0;
    s[t] = vv;
    __syncthreads();
    for (int d = 1; d < 256; d <<= 1) {
        int add = (t >= d) ? s[t - d] : 0;
        __syncthreads();
        s[t] += add;
        __syncthreads();
    }
    if (i < N_NODES) rowptr[i] = s[t] - vv;
    if (t == 255) bsum[blockIdx.x] = s[255];
}

__global__ __launch_bounds__(512) void k_scan2(int* __restrict__ bsum, int nb) {
    __shared__ int s[512];
    int t = threadIdx.x;
    int vv = (t < nb) ? bsum[t] : 0;
    s[t] = vv;
    __syncthreads();
    for (int d = 1; d < 512; d <<= 1) {
        int add = (t >= d) ? s[t - d] : 0;
        __syncthreads();
        s[t] += add;
        __syncthreads();
    }
    if (t < nb) bsum[t] = s[t] - vv;
}

__global__ __launch_bounds__(256) void k_scan3(int* __restrict__ rowptr,
                                               const int* __restrict__ bsum,
                                               int* __restrict__ wofs) {
    int i = blockIdx.x * 256 + threadIdx.x;
    if (i < N_NODES) {
        int r = rowptr[i] + bsum[blockIdx.x];
        rowptr[i] = r;
        wofs[i] = r;
    }
    if (i == 0) rowptr[N_NODES] = N_EDGES;
}

// ---------------- scatter edges into CSR order ----------------------------
__global__ void k_scatter(const int* __restrict__ src, const int* __restrict__ tgt,
                          int* __restrict__ wofs, int* __restrict__ stgt) {
    int i = blockIdx.x * 256 + threadIdx.x;
    int stride = gridDim.x * 256;
    for (; i < N_EDGES; i += stride) {
        int p = atomicAdd(&wofs[src[i]], 1);
        stgt[p] = tgt[i];
    }
}

// ---------------- SpMM: out[s][h*64+f] = sum_e w * Wh[t][h*64+f] / sum w --
__global__ __launch_bounds__(256) void k_spmm(const int* __restrict__ rowptr,
                                              const int* __restrict__ stgt,
                                              const float* __restrict__ asrc,
                                              const float* __restrict__ atgt,
                                              const unsigned short* __restrict__ Wh,
                                              float* __restrict__ out) {
    int task = (blockIdx.x * 256 + threadIdx.x) >> 6;   // (node, head), 800000 total
    int lane = threadIdx.x & 63;
    int s = task >> 3, h = task & 7;
    int base = rowptr[s], end = rowptr[s + 1];
    float a_s = asrc[s * 8 + h];
    float acc = 0.f, den = 0.f;
    const unsigned short* Whh = Wh + h * 64 + lane;
    for (int c0 = base; c0 < end; c0 += 64) {
        int j = c0 + lane;
        int t = 0;
        float w = 0.f;
        if (j < end) {
            t = stgt[j];
            float z = a_s + atgt[t * 8 + h];
            float e = (z > 0.f) ? -z : -(ALPHA * z);
            w = __expf(e);
        }
        float ws = w;
        for (int d = 1; d < 64; d <<= 1) ws += __shfl_xor(ws, d);
        den += ws;
        int cnt = end - c0;
        if (cnt > 64) cnt = 64;
#pragma unroll 4
        for (int jj = 0; jj < cnt; ++jj) {
            int tj = __shfl(t, jj);
            float wj = __shfl(w, jj);
            float val = b2f(Whh[(size_t)tj * 512]);
            acc = fmaf(wj, val, acc);
        }
    }
    out[(size_t)s * 512 + h * 64 + lane] = acc / (den + 1e-10f);
}

extern "C" void kernel_launch(void* const* d_in, const int* in_sizes, int n_in,
                              void* d_out, int out_size, void* d_ws, size_t ws_size,
                              hipStream_t stream) {
    const float* x = (const float*)d_in[0];
    const int* edges = (const int*)d_in[1];
    const float* W = (const float*)d_in[2];
    const float* a = (const float*)d_in[3];
    float* out = (float*)d_out;
    const int* src = edges;
    const int* tgt = edges + N_EDGES;

    char* ws = (char*)d_ws;
    size_t off = 0;
    auto alloc = [&](size_t bytes) -> void* {
        void* p = (void*)(ws + off);
        off += (bytes + 255) & ~(size_t)255;
        return p;
    };
    unsigned short* Wh = (unsigned short*)alloc((size_t)N_NODES * 512 * 2);  // 102.4 MB
    unsigned short* Wt = (unsigned short*)alloc((size_t)HEADS * OUT_F * IN_F * 2);
    float* u = (float*)alloc(HEADS * IN_F * 4);
    float* v = (float*)alloc(HEADS * IN_F * 4);
    float* asrc = (float*)alloc((size_t)N_NODES * 8 * 4);
    float* atgt = (float*)alloc((size_t)N_NODES * 8 * 4);
    int* count = (int*)alloc((size_t)N_NODES * 4);
    int* rowptr = (int*)alloc((size_t)(N_NODES + 1) * 4);
    int* bsum = (int*)alloc(512 * 4);
    int* wofs = (int*)alloc((size_t)N_NODES * 4);
    int* stgt = (int*)alloc((size_t)N_EDGES * 4);
    (void)ws_size; (void)n_in; (void)in_sizes; (void)out_size;

    hipMemsetAsync(count, 0, (size_t)N_NODES * 4, stream);
    k_prep_w<<<256, 256, 0, stream>>>(W, Wt);
    k_uv<<<1, 1024, 0, stream>>>(W, a, u, v);
    k_gemm<<<1563, 256, 0, stream>>>(x, Wt, Wh);
    k_adot<<<25000, 256, 0, stream>>>(x, u, v, asrc, atgt);
    k_hist<<<2048, 256, 0, stream>>>(src, count);
    k_scan1<<<391, 256, 0, stream>>>(count, rowptr, bsum);
    k_scan2<<<1, 512, 0, stream>>>(bsum, 391);
    k_scan3<<<391, 256, 0, stream>>>(rowptr, bsum, wofs);
    k_scatter<<<2048, 256, 0, stream>>>(src, tgt, wofs, stgt);
    k_spmm<<<200000, 256, 0, stream>>>(rowptr, stgt, asrc, atgt, Wh, out);
}

// Round 2
// 1057.770 us; speedup vs baseline: 1.7445x; 1.7445x over previous
//
#include <hip/hip_runtime.h>
#include <hip/hip_bf16.h>

#define N_NODES 100000
#define N_EDGES 3200000
#define IN_F 128
#define OUT_F 64
#define HEADS 8
#define ALPHA 0.2f

typedef __bf16 bf16x8 __attribute__((ext_vector_type(8)));
typedef float f32x4 __attribute__((ext_vector_type(4)));
typedef __attribute__((ext_vector_type(8))) unsigned short ushort8;

static __device__ __forceinline__ unsigned short f2b(float f) {
    __hip_bfloat16 h = __float2bfloat16(f);
    return __builtin_bit_cast(unsigned short, h);
}
static __device__ __forceinline__ float b2f(unsigned short u) {
    unsigned int x = ((unsigned int)u) << 16;
    return __builtin_bit_cast(float, x);
}

// ---------------- W transpose+convert: Wt[c=h*64+f][k] bf16 ----------------
__global__ void k_prep_w(const float* __restrict__ W, unsigned short* __restrict__ Wt) {
    int idx = blockIdx.x * 256 + threadIdx.x;   // = c*128 + k, total 65536
    if (idx >= HEADS * OUT_F * IN_F) return;
    int k = idx & 127;
    int c = idx >> 7;
    int h = c >> 6;
    int f = c & 63;
    Wt[idx] = f2b(W[h * IN_F * OUT_F + k * OUT_F + f]);
}

// ---------------- u[h][k] = sum_f W[h][k][f]*a[h][f]; v with a[h][64+f] ----
__global__ __launch_bounds__(1024) void k_uv(const float* __restrict__ W,
                                             const float* __restrict__ a,
                                             float* __restrict__ u, float* __restrict__ v) {
    int t = threadIdx.x;          // 1024 = 8 heads * 128 k
    int h = t >> 7, k = t & 127;
    const float* Wrow = W + h * IN_F * OUT_F + k * OUT_F;
    const float* ah = a + h * 2 * OUT_F;
    float su = 0.f, sv = 0.f;
    for (int f = 0; f < OUT_F; ++f) {
        float wv = Wrow[f];
        su += wv * ah[f];
        sv += wv * ah[OUT_F + f];
    }
    u[t] = su;
    v[t] = sv;
}

// ---------------- GEMM: Wh[n][512] bf16 = x[n][128] @ Wt^T -----------------
#define LDK 136   // padded K stride (bf16 elems)
__global__ __launch_bounds__(256) void k_gemm(const float* __restrict__ x,
                                              const unsigned short* __restrict__ Wt,
                                              unsigned short* __restrict__ Wh) {
    __shared__ unsigned short Al[64 * LDK];
    __shared__ unsigned short Bl[128 * LDK];
    const int tid = threadIdx.x;
    const int tile0 = blockIdx.x * 64;
    // stage A (x tile, fp32 -> bf16): 64 rows x 128 k
    for (int it = 0; it < 8; ++it) {
        int idx = tid + it * 256;            // 0..2047 float4s
        int r = idx >> 5;
        int k4 = (idx & 31) << 2;
        int gr = tile0 + r;
        if (gr >= N_NODES) gr = N_NODES - 1;
        const float4 xv = *reinterpret_cast<const float4*>(x + (size_t)gr * IN_F + k4);
        ushort4 pv = make_ushort4(f2b(xv.x), f2b(xv.y), f2b(xv.z), f2b(xv.w));
        *reinterpret_cast<ushort4*>(&Al[r * LDK + k4]) = pv;
    }
    const int lane = tid & 63, wid = tid >> 6;
    const int wr = wid >> 1, wc = wid & 1;   // wave tile: rows wr*32, cols wc*64
    const int l15 = lane & 15, lq = lane >> 4;

    for (int g = 0; g < 4; ++g) {
        __syncthreads();
        // stage B: global cols g*128 .. g*128+127, layout Bl[c][k]
        for (int it = 0; it < 8; ++it) {
            int idx = tid + it * 256;        // 0..2047 vec8s
            int c = idx >> 4;
            int k8 = (idx & 15) << 3;
            *reinterpret_cast<ushort8*>(&Bl[c * LDK + k8]) =
                *reinterpret_cast<const ushort8*>(Wt + (size_t)(g * 128 + c) * IN_F + k8);
        }
        __syncthreads();

        f32x4 acc[2][4] = {};
        for (int ks = 0; ks < 4; ++ks) {
            int koff = ks * 32 + lq * 8;
            bf16x8 af[2], bfr[4];
            for (int m = 0; m < 2; ++m)
                af[m] = *reinterpret_cast<const bf16x8*>(&Al[(wr * 32 + m * 16 + l15) * LDK + koff]);
            for (int n = 0; n < 4; ++n)
                bfr[n] = *reinterpret_cast<const bf16x8*>(&Bl[(wc * 64 + n * 16 + l15) * LDK + koff]);
            for (int m = 0; m < 2; ++m)
                for (int n = 0; n < 4; ++n)
                    acc[m][n] = __builtin_amdgcn_mfma_f32_16x16x32_bf16(af[m], bfr[n], acc[m][n], 0, 0, 0);
        }
        // epilogue: D col = lane&15, row = (lane>>4)*4 + reg
        for (int m = 0; m < 2; ++m)
            for (int n = 0; n < 4; ++n) {
                int row0 = tile0 + wr * 32 + m * 16 + lq * 4;
                int colg = g * 128 + wc * 64 + n * 16 + l15;
                for (int r2 = 0; r2 < 4; ++r2) {
                    int rr = row0 + r2;
                    if (rr < N_NODES)
                        Wh[(size_t)rr * 512 + colg] = f2b(acc[m][n][r2]);
                }
            }
    }
}

// ---------------- logits: asrc[n][h] = x[n]·u[h], atgt[n][h] = x[n]·v[h] ---
__global__ __launch_bounds__(256) void k_adot(const float* __restrict__ x,
                                              const float* __restrict__ u,
                                              const float* __restrict__ v,
                                              float* __restrict__ asrc,
                                              float* __restrict__ atgt) {
    int node = (blockIdx.x * 256 + threadIdx.x) >> 6;
    int lane = threadIdx.x & 63;
    if (node >= N_NODES) return;
    float xa = x[(size_t)node * 128 + lane];
    float xb = x[(size_t)node * 128 + 64 + lane];
    for (int h = 0; h < 8; ++h) {
        float s1 = xa * u[h * 128 + lane] + xb * u[h * 128 + 64 + lane];
        float s2 = xa * v[h * 128 + lane] + xb * v[h * 128 + 64 + lane];
        for (int d = 1; d < 64; d <<= 1) {
            s1 += __shfl_xor(s1, d);
            s2 += __shfl_xor(s2, d);
        }
        if (lane == 0) {
            asrc[node * 8 + h] = s1;
            atgt[node * 8 + h] = s2;
        }
    }
}

// ---------------- histogram over src --------------------------------------
__global__ void k_hist(const int* __restrict__ src, int* __restrict__ count) {
    int i = blockIdx.x * 256 + threadIdx.x;
    int stride = gridDim.x * 256;
    for (; i < N_EDGES; i += stride) atomicAdd(&count[src[i]], 1);
}

// ---------------- 3-kernel exclusive scan ---------------------------------
__global__ __launch_bounds__(256) void k_scan1(const int* __restrict__ count,
                                               int* __restrict__ rowptr,
                                               int* __restrict__ bsum) {
    __shared__ int s[256];
    int t = threadIdx.x;
    int i = blockIdx.x * 256 + t;
    int vv = (i < N_NODES) ? count[i] : 0;
    s[t] = vv;
    __syncthreads();
    for (int d = 1; d < 256; d <<= 1) {
        int add = (t >= d) ? s[t - d] : 0;
        __syncthreads();
        s[t] += add;
        __syncthreads();
    }
    if (i < N_NODES) rowptr[i] = s[t] - vv;
    if (t == 255) bsum[blockIdx.x] = s[255];
}

__global__ __launch_bounds__(512) void k_scan2(int* __restrict__ bsum, int nb) {
    __shared__ int s[512];
    int t = threadIdx.x;
    int vv = (t < nb) ? bsum[t] : 0;
    s[t] = vv;
    __syncthreads();
    for (int d = 1; d < 512; d <<= 1) {
        int add = (t >= d) ? s[t - d] : 0;
        __syncthreads();
        s[t] += add;
        __syncthreads();
    }
    if (t < nb) bsum[t] = s[t] - vv;
}

__global__ __launch_bounds__(256) void k_scan3(int* __restrict__ rowptr,
                                               const int* __restrict__ bsum,
                                               int* __restrict__ wofs) {
    int i = blockIdx.x * 256 + threadIdx.x;
    if (i < N_NODES) {
        int r = rowptr[i] + bsum[blockIdx.x];
        rowptr[i] = r;
        wofs[i] = r;
    }
    if (i == 0) rowptr[N_NODES] = N_EDGES;
}

// ---------------- scatter edges into CSR order ----------------------------
__global__ void k_scatter(const int* __restrict__ src, const int* __restrict__ tgt,
                          int* __restrict__ wofs, int* __restrict__ stgt) {
    int i = blockIdx.x * 256 + threadIdx.x;
    int stride = gridDim.x * 256;
    for (; i < N_EDGES; i += stride) {
        int p = atomicAdd(&wofs[src[i]], 1);
        stgt[p] = tgt[i];
    }
}

// ---------------- SpMM v2: one wave per node, full 512-feature row --------
// lane l owns flat features [l*8, l*8+8) -> head h = l>>3; all 8 lanes of a
// head group compute the same edge weight, so den needs no cross-lane reduce.
__global__ __launch_bounds__(256) void k_spmm2(const int* __restrict__ rowptr,
                                               const int* __restrict__ stgt,
                                               const float* __restrict__ asrc,
                                               const float* __restrict__ atgt,
                                               const unsigned short* __restrict__ Wh,
                                               float* __restrict__ out) {
    int node = (blockIdx.x * 256 + threadIdx.x) >> 6;
    int lane = threadIdx.x & 63;
    if (node >= N_NODES) return;
    int base = rowptr[node], end = rowptr[node + 1];
    int h = lane >> 3;
    float a_s = asrc[node * 8 + h];
    float acc[8] = {0.f, 0.f, 0.f, 0.f, 0.f, 0.f, 0.f, 0.f};
    float den = 0.f;
    const unsigned short* __restrict__ Whl = Wh + lane * 8;

    for (int c0 = base; c0 < end; c0 += 64) {
        int j = c0 + lane;
        int t = (j < end) ? stgt[j] : 0;
        int cnt = end - c0;
        if (cnt > 64) cnt = 64;
#pragma unroll 4
        for (int jj = 0; jj < cnt; ++jj) {
            int tj = __shfl(t, jj);
            // row gather: 16B/lane -> 1024B contiguous per wave
            ushort8 rv = *reinterpret_cast<const ushort8*>(Whl + (size_t)tj * 512);
            float at = atgt[tj * 8 + h];     // 32B broadcast segment
            float z = a_s + at;
            float e = (z > 0.f) ? -z : -(ALPHA * z);
            float w = __expf(e);
            den += w;
#pragma unroll
            for (int i = 0; i < 8; ++i)
                acc[i] = fmaf(w, b2f(rv[i]), acc[i]);
        }
    }
    float inv = 1.f / (den + 1e-10f);
    float* op = out + (size_t)node * 512 + lane * 8;
    float4 o0 = make_float4(acc[0] * inv, acc[1] * inv, acc[2] * inv, acc[3] * inv);
    float4 o1 = make_float4(acc[4] * inv, acc[5] * inv, acc[6] * inv, acc[7] * inv);
    *reinterpret_cast<float4*>(op) = o0;
    *reinterpret_cast<float4*>(op + 4) = o1;
}

extern "C" void kernel_launch(void* const* d_in, const int* in_sizes, int n_in,
                              void* d_out, int out_size, void* d_ws, size_t ws_size,
                              hipStream_t stream) {
    const float* x = (const float*)d_in[0];
    const int* edges = (const int*)d_in[1];
    const float* W = (const float*)d_in[2];
    const float* a = (const float*)d_in[3];
    float* out = (float*)d_out;
    const int* src = edges;
    const int* tgt = edges + N_EDGES;

    char* ws = (char*)d_ws;
    size_t off = 0;
    auto alloc = [&](size_t bytes) -> void* {
        void* p = (void*)(ws + off);
        off += (bytes + 255) & ~(size_t)255;
        return p;
    };
    unsigned short* Wh = (unsigned short*)alloc((size_t)N_NODES * 512 * 2);  // 102.4 MB
    unsigned short* Wt = (unsigned short*)alloc((size_t)HEADS * OUT_F * IN_F * 2);
    float* u = (float*)alloc(HEADS * IN_F * 4);
    float* v = (float*)alloc(HEADS * IN_F * 4);
    float* asrc = (float*)alloc((size_t)N_NODES * 8 * 4);
    float* atgt = (float*)alloc((size_t)N_NODES * 8 * 4);
    int* count = (int*)alloc((size_t)N_NODES * 4);
    int* rowptr = (int*)alloc((size_t)(N_NODES + 1) * 4);
    int* bsum = (int*)alloc(512 * 4);
    int* wofs = (int*)alloc((size_t)N_NODES * 4);
    int* stgt = (int*)alloc((size_t)N_EDGES * 4);
    (void)ws_size; (void)n_in; (void)in_sizes; (void)out_size;

    hipMemsetAsync(count, 0, (size_t)N_NODES * 4, stream);
    k_prep_w<<<256, 256, 0, stream>>>(W, Wt);
    k_uv<<<1, 1024, 0, stream>>>(W, a, u, v);
    k_gemm<<<1563, 256, 0, stream>>>(x, Wt, Wh);
    k_adot<<<25000, 256, 0, stream>>>(x, u, v, asrc, atgt);
    k_hist<<<2048, 256, 0, stream>>>(src, count);
    k_scan1<<<391, 256, 0, stream>>>(count, rowptr, bsum);
    k_scan2<<<1, 512, 0, stream>>>(bsum, 391);
    k_scan3<<<391, 256, 0, stream>>>(rowptr, bsum, wofs);
    k_scatter<<<2048, 256, 0, stream>>>(src, tgt, wofs, stgt);
    k_spmm2<<<25000, 256, 0, stream>>>(rowptr, stgt, asrc, atgt, Wh, out);
}

// Round 3
// 843.735 us; speedup vs baseline: 2.1870x; 1.2537x over previous
//
#include <hip/hip_runtime.h>
#include <hip/hip_bf16.h>

#define N_NODES 100000
#define N_EDGES 3200000
#define IN_F 128
#define OUT_F 64
#define HEADS 8
#define ALPHA 0.2f

typedef __bf16 bf16x8 __attribute__((ext_vector_type(8)));
typedef float f32x4 __attribute__((ext_vector_type(4)));
typedef __attribute__((ext_vector_type(8))) unsigned short ushort8;

static __device__ __forceinline__ unsigned short f2b(float f) {
    __hip_bfloat16 h = __float2bfloat16(f);
    return __builtin_bit_cast(unsigned short, h);
}
static __device__ __forceinline__ float b2f(unsigned short u) {
    unsigned int x = ((unsigned int)u) << 16;
    return __builtin_bit_cast(float, x);
}

// ---------------- W transpose+convert: Wt[c=h*64+f][k] bf16 ----------------
__global__ void k_prep_w(const float* __restrict__ W, unsigned short* __restrict__ Wt) {
    int idx = blockIdx.x * 256 + threadIdx.x;   // = c*128 + k, total 65536
    if (idx >= HEADS * OUT_F * IN_F) return;
    int k = idx & 127;
    int c = idx >> 7;
    int h = c >> 6;
    int f = c & 63;
    Wt[idx] = f2b(W[h * IN_F * OUT_F + k * OUT_F + f]);
}

// ---------------- u[h][k] = sum_f W[h][k][f]*a[h][f]; v with a[h][64+f] ----
__global__ __launch_bounds__(1024) void k_uv(const float* __restrict__ W,
                                             const float* __restrict__ a,
                                             float* __restrict__ u, float* __restrict__ v) {
    int t = threadIdx.x;          // 1024 = 8 heads * 128 k
    int h = t >> 7, k = t & 127;
    const float* Wrow = W + h * IN_F * OUT_F + k * OUT_F;
    const float* ah = a + h * 2 * OUT_F;
    float su = 0.f, sv = 0.f;
    for (int f = 0; f < OUT_F; ++f) {
        float wv = Wrow[f];
        su += wv * ah[f];
        sv += wv * ah[OUT_F + f];
    }
    u[t] = su;
    v[t] = sv;
}

// ------- fused: x -> bf16 copy, and logits asrc/atgt via u,v dots ----------
__global__ __launch_bounds__(256) void k_xadot(const float* __restrict__ x,
                                               const float* __restrict__ u,
                                               const float* __restrict__ v,
                                               unsigned short* __restrict__ xb,
                                               float* __restrict__ asrc,
                                               float* __restrict__ atgt) {
    int node = (blockIdx.x * 256 + threadIdx.x) >> 6;
    int lane = threadIdx.x & 63;
    if (node >= N_NODES) return;
    float2 xv = *reinterpret_cast<const float2*>(x + (size_t)node * 128 + 2 * lane);
    ushort2 pv = make_ushort2(f2b(xv.x), f2b(xv.y));
    *reinterpret_cast<ushort2*>(xb + (size_t)node * 128 + 2 * lane) = pv;
    for (int h = 0; h < 8; ++h) {
        float2 uu = *reinterpret_cast<const float2*>(u + h * 128 + 2 * lane);
        float2 vv = *reinterpret_cast<const float2*>(v + h * 128 + 2 * lane);
        float s1 = xv.x * uu.x + xv.y * uu.y;
        float s2 = xv.x * vv.x + xv.y * vv.y;
        for (int d = 1; d < 64; d <<= 1) {
            s1 += __shfl_xor(s1, d);
            s2 += __shfl_xor(s2, d);
        }
        if (lane == 0) {
            asrc[node * 8 + h] = s1;
            atgt[node * 8 + h] = s2;
        }
    }
}

// ---------------- histogram over src --------------------------------------
__global__ void k_hist(const int* __restrict__ src, int* __restrict__ count) {
    int i = blockIdx.x * 256 + threadIdx.x;
    int stride = gridDim.x * 256;
    for (; i < N_EDGES; i += stride) atomicAdd(&count[src[i]], 1);
}

// ---------------- 3-kernel exclusive scan ---------------------------------
__global__ __launch_bounds__(256) void k_scan1(const int* __restrict__ count,
                                               int* __restrict__ rowptr,
                                               int* __restrict__ bsum) {
    __shared__ int s[256];
    int t = threadIdx.x;
    int i = blockIdx.x * 256 + t;
    int vv = (i < N_NODES) ? count[i] : 0;
    s[t] = vv;
    __syncthreads();
    for (int d = 1; d < 256; d <<= 1) {
        int add = (t >= d) ? s[t - d] : 0;
        __syncthreads();
        s[t] += add;
        __syncthreads();
    }
    if (i < N_NODES) rowptr[i] = s[t] - vv;
    if (t == 255) bsum[blockIdx.x] = s[255];
}

__global__ __launch_bounds__(512) void k_scan2(int* __restrict__ bsum, int nb) {
    __shared__ int s[512];
    int t = threadIdx.x;
    int vv = (t < nb) ? bsum[t] : 0;
    s[t] = vv;
    __syncthreads();
    for (int d = 1; d < 512; d <<= 1) {
        int add = (t >= d) ? s[t - d] : 0;
        __syncthreads();
        s[t] += add;
        __syncthreads();
    }
    if (t < nb) bsum[t] = s[t] - vv;
}

__global__ __launch_bounds__(256) void k_scan3(int* __restrict__ rowptr,
                                               const int* __restrict__ bsum,
                                               int* __restrict__ wofs) {
    int i = blockIdx.x * 256 + threadIdx.x;
    if (i < N_NODES) {
        int r = rowptr[i] + bsum[blockIdx.x];
        rowptr[i] = r;
        wofs[i] = r;
    }
    if (i == 0) rowptr[N_NODES] = N_EDGES;
}

// ---------------- scatter edges into CSR order ----------------------------
__global__ void k_scatter(const int* __restrict__ src, const int* __restrict__ tgt,
                          int* __restrict__ wofs, int* __restrict__ stgt) {
    int i = blockIdx.x * 256 + threadIdx.x;
    int stride = gridDim.x * 256;
    for (; i < N_EDGES; i += stride) {
        int p = atomicAdd(&wofs[src[i]], 1);
        stgt[p] = tgt[i];
    }
}

// ------- aggregate raw x rows with per-head softmax weights ---------------
// one wave per node; lane l: head h=l>>3, feature group g=l&7 (16 feats).
// Writes normalized aggregate as bf16 [node][h][128] INTO d_out (same size).
__global__ __launch_bounds__(256) void k_agg(const int* __restrict__ rowptr,
                                             const int* __restrict__ stgt,
                                             const float* __restrict__ asrc,
                                             const float* __restrict__ atgt,
                                             const unsigned short* __restrict__ xb,
                                             unsigned short* __restrict__ agg) {
    int node = (blockIdx.x * 256 + threadIdx.x) >> 6;
    int lane = threadIdx.x & 63;
    if (node >= N_NODES) return;
    int base = rowptr[node], end = rowptr[node + 1];
    int h = lane >> 3, g = lane & 7;
    float a_s = asrc[node * 8 + h];
    float acc[16] = {};
    float den = 0.f;
    const unsigned short* __restrict__ xg = xb + g * 16;

    for (int c0 = base; c0 < end; c0 += 64) {
        int j = c0 + lane;
        int t = (j < end) ? stgt[j] : 0;
        int cnt = end - c0;
        if (cnt > 64) cnt = 64;
#pragma unroll 4
        for (int jj = 0; jj < cnt; ++jj) {
            int tj = __shfl(t, jj);
            ushort8 r0 = *reinterpret_cast<const ushort8*>(xg + (size_t)tj * 128);
            ushort8 r1 = *reinterpret_cast<const ushort8*>(xg + (size_t)tj * 128 + 8);
            float at = atgt[tj * 8 + h];
            float z = a_s + at;
            float e = (z > 0.f) ? -z : -(ALPHA * z);
            float w = __expf(e);
            den += w;
#pragma unroll
            for (int i = 0; i < 8; ++i) acc[i] = fmaf(w, b2f(r0[i]), acc[i]);
#pragma unroll
            for (int i = 0; i < 8; ++i) acc[8 + i] = fmaf(w, b2f(r1[i]), acc[8 + i]);
        }
    }
    float inv = 1.f / (den + 1e-10f);
    ushort8 o0, o1;
#pragma unroll
    for (int i = 0; i < 8; ++i) {
        o0[i] = f2b(acc[i] * inv);
        o1[i] = f2b(acc[8 + i] * inv);
    }
    unsigned short* op = agg + (size_t)node * 1024 + h * 128 + g * 16;
    *reinterpret_cast<ushort8*>(op) = o0;
    *reinterpret_cast<ushort8*>(op + 8) = o1;
}

// ------- final per-head GEMM: out[r][h*64+f] = agg[r][h][:] @ W[h][:][f] ---
// In-place over d_out: block (h, row-tile) reads byte range [r*2048+h*256,
// +256) (bf16 agg slice) and writes the SAME range as fp32 out slice —
// disjoint across blocks, staged to LDS before any write.
#define LDK2 136
__global__ __launch_bounds__(256) void k_gemm2(const unsigned short* __restrict__ agg,
                                               const unsigned short* __restrict__ Wt,
                                               float* __restrict__ out) {
    __shared__ unsigned short Al[64 * LDK2];
    __shared__ unsigned short Bl[64 * LDK2];
    const int tid = threadIdx.x;
    const int h = blockIdx.y;
    const int r0 = blockIdx.x * 64;
    for (int it = 0; it < 4; ++it) {
        int idx = tid + it * 256;            // 0..1023 ushort8
        int r = idx >> 4, k8 = (idx & 15) << 3;
        int gr = r0 + r;
        if (gr >= N_NODES) gr = N_NODES - 1;
        *reinterpret_cast<ushort8*>(&Al[r * LDK2 + k8]) =
            *reinterpret_cast<const ushort8*>(agg + (size_t)gr * 1024 + h * 128 + k8);
    }
    for (int it = 0; it < 4; ++it) {
        int idx = tid + it * 256;
        int f = idx >> 4, k8 = (idx & 15) << 3;
        *reinterpret_cast<ushort8*>(&Bl[f * LDK2 + k8]) =
            *reinterpret_cast<const ushort8*>(Wt + (size_t)(h * 64 + f) * 128 + k8);
    }
    __syncthreads();
    const int lane = tid & 63, w = tid >> 6;
    const int l15 = lane & 15, lq = lane >> 4;
    f32x4 acc[4] = {};
    for (int ks = 0; ks < 4; ++ks) {
        int koff = ks * 32 + lq * 8;
        bf16x8 af = *reinterpret_cast<const bf16x8*>(&Al[(w * 16 + l15) * LDK2 + koff]);
#pragma unroll
        for (int n = 0; n < 4; ++n) {
            bf16x8 bf_ = *reinterpret_cast<const bf16x8*>(&Bl[(n * 16 + l15) * LDK2 + koff]);
            acc[n] = __builtin_amdgcn_mfma_f32_16x16x32_bf16(af, bf_, acc[n], 0, 0, 0);
        }
    }
    for (int n = 0; n < 4; ++n) {
        int col = h * 64 + n * 16 + l15;
        int rbase = r0 + w * 16 + lq * 4;
#pragma unroll
        for (int r2 = 0; r2 < 4; ++r2) {
            int rr = rbase + r2;
            if (rr < N_NODES) out[(size_t)rr * 512 + col] = acc[n][r2];
        }
    }
}

extern "C" void kernel_launch(void* const* d_in, const int* in_sizes, int n_in,
                              void* d_out, int out_size, void* d_ws, size_t ws_size,
                              hipStream_t stream) {
    const float* x = (const float*)d_in[0];
    const int* edges = (const int*)d_in[1];
    const float* W = (const float*)d_in[2];
    const float* a = (const float*)d_in[3];
    float* out = (float*)d_out;
    const int* src = edges;
    const int* tgt = edges + N_EDGES;

    char* ws = (char*)d_ws;
    size_t off = 0;
    auto alloc = [&](size_t bytes) -> void* {
        void* p = (void*)(ws + off);
        off += (bytes + 255) & ~(size_t)255;
        return p;
    };
    unsigned short* Wt = (unsigned short*)alloc((size_t)HEADS * OUT_F * IN_F * 2);
    float* u = (float*)alloc(HEADS * IN_F * 4);
    float* v = (float*)alloc(HEADS * IN_F * 4);
    unsigned short* xb = (unsigned short*)alloc((size_t)N_NODES * IN_F * 2);  // 25.6 MB
    float* asrc = (float*)alloc((size_t)N_NODES * 8 * 4);
    float* atgt = (float*)alloc((size_t)N_NODES * 8 * 4);
    int* count = (int*)alloc((size_t)N_NODES * 4);
    int* rowptr = (int*)alloc((size_t)(N_NODES + 1) * 4);
    int* bsum = (int*)alloc(512 * 4);
    int* wofs = (int*)alloc((size_t)N_NODES * 4);
    int* stgt = (int*)alloc((size_t)N_EDGES * 4);
    (void)ws_size; (void)n_in; (void)in_sizes; (void)out_size;

    hipMemsetAsync(count, 0, (size_t)N_NODES * 4, stream);
    k_prep_w<<<256, 256, 0, stream>>>(W, Wt);
    k_uv<<<1, 1024, 0, stream>>>(W, a, u, v);
    k_xadot<<<25000, 256, 0, stream>>>(x, u, v, xb, asrc, atgt);
    k_hist<<<2048, 256, 0, stream>>>(src, count);
    k_scan1<<<391, 256, 0, stream>>>(count, rowptr, bsum);
    k_scan2<<<1, 512, 0, stream>>>(bsum, 391);
    k_scan3<<<391, 256, 0, stream>>>(rowptr, bsum, wofs);
    k_scatter<<<2048, 256, 0, stream>>>(src, tgt, wofs, stgt);
    k_agg<<<25000, 256, 0, stream>>>(rowptr, stgt, asrc, atgt, xb,
                                     (unsigned short*)d_out);
    k_gemm2<<<dim3(1563, 8), 256, 0, stream>>>((const unsigned short*)d_out, Wt, out);
}

// Round 4
// 592.525 us; speedup vs baseline: 3.1142x; 1.4240x over previous
//
#include <hip/hip_runtime.h>
#include <hip/hip_bf16.h>

#define N_NODES 100000
#define N_EDGES 3200000
#define IN_F 128
#define OUT_F 64
#define HEADS 8
#define ALPHA 0.2f

#define BSHIFT 7
#define NBUCK 782           // ceil(100000 / 128)
#define CHUNK 16384         // edges per partition block
#define NPBLK 196           // ceil(N_EDGES / CHUNK)

typedef __bf16 bf16x8 __attribute__((ext_vector_type(8)));
typedef float f32x4 __attribute__((ext_vector_type(4)));
typedef __attribute__((ext_vector_type(8))) unsigned short ushort8;

static __device__ __forceinline__ unsigned short f2b(float f) {
    __hip_bfloat16 h = __float2bfloat16(f);
    return __builtin_bit_cast(unsigned short, h);
}
static __device__ __forceinline__ float b2f(unsigned short u) {
    unsigned int x = ((unsigned int)u) << 16;
    return __builtin_bit_cast(float, x);
}

// ---------------- W transpose+convert: Wt[c=h*64+f][k] bf16 ----------------
__global__ void k_prep_w(const float* __restrict__ W, unsigned short* __restrict__ Wt) {
    int idx = blockIdx.x * 256 + threadIdx.x;
    if (idx >= HEADS * OUT_F * IN_F) return;
    int k = idx & 127;
    int c = idx >> 7;
    int h = c >> 6;
    int f = c & 63;
    Wt[idx] = f2b(W[h * IN_F * OUT_F + k * OUT_F + f]);
}

// ---------------- u[h][k] = sum_f W[h][k][f]*a[h][f]; v with a[h][64+f] ----
__global__ __launch_bounds__(1024) void k_uv(const float* __restrict__ W,
                                             const float* __restrict__ a,
                                             float* __restrict__ u, float* __restrict__ v) {
    int t = threadIdx.x;
    int h = t >> 7, k = t & 127;
    const float* Wrow = W + h * IN_F * OUT_F + k * OUT_F;
    const float* ah = a + h * 2 * OUT_F;
    float su = 0.f, sv = 0.f;
    for (int f = 0; f < OUT_F; ++f) {
        float wv = Wrow[f];
        su += wv * ah[f];
        sv += wv * ah[OUT_F + f];
    }
    u[t] = su;
    v[t] = sv;
}

// ------- fused: x -> bf16 copy, and logits asrc/atgt via u,v dots ----------
__global__ __launch_bounds__(256) void k_xadot(const float* __restrict__ x,
                                               const float* __restrict__ u,
                                               const float* __restrict__ v,
                                               unsigned short* __restrict__ xb,
                                               float* __restrict__ asrc,
                                               float* __restrict__ atgt) {
    int node = (blockIdx.x * 256 + threadIdx.x) >> 6;
    int lane = threadIdx.x & 63;
    if (node >= N_NODES) return;
    float2 xv = *reinterpret_cast<const float2*>(x + (size_t)node * 128 + 2 * lane);
    ushort2 pv = make_ushort2(f2b(xv.x), f2b(xv.y));
    *reinterpret_cast<ushort2*>(xb + (size_t)node * 128 + 2 * lane) = pv;
    for (int h = 0; h < 8; ++h) {
        float2 uu = *reinterpret_cast<const float2*>(u + h * 128 + 2 * lane);
        float2 vv = *reinterpret_cast<const float2*>(v + h * 128 + 2 * lane);
        float s1 = xv.x * uu.x + xv.y * uu.y;
        float s2 = xv.x * vv.x + xv.y * vv.y;
        for (int d = 1; d < 64; d <<= 1) {
            s1 += __shfl_xor(s1, d);
            s2 += __shfl_xor(s2, d);
        }
        if (lane == 0) {
            asrc[node * 8 + h] = s1;
            atgt[node * 8 + h] = s2;
        }
    }
}

// ---------------- pass 0: global bucket histogram (LDS-privatized) --------
__global__ __launch_bounds__(256) void k_bcount(const int* __restrict__ src,
                                                int* __restrict__ bhist) {
    __shared__ int h[NBUCK];
    for (int i = threadIdx.x; i < NBUCK; i += 256) h[i] = 0;
    __syncthreads();
    int i0 = blockIdx.x * CHUNK;
    int iend = i0 + CHUNK;
    if (iend > N_EDGES) iend = N_EDGES;
    for (int i = i0 + threadIdx.x; i < iend; i += 256)
        atomicAdd(&h[src[i] >> BSHIFT], 1);
    __syncthreads();
    for (int i = threadIdx.x; i < NBUCK; i += 256)
        if (h[i]) atomicAdd(&bhist[i], h[i]);
}

// ---------------- bucket scan (1 block); also init cursors ----------------
__global__ __launch_bounds__(1024) void k_bscan(const int* __restrict__ bhist,
                                                int* __restrict__ bstart,
                                                int* __restrict__ bcursor,
                                                int* __restrict__ rowptr) {
    __shared__ int s[1024];
    int t = threadIdx.x;
    int v = (t < NBUCK) ? bhist[t] : 0;
    s[t] = v;
    __syncthreads();
    for (int d = 1; d < 1024; d <<= 1) {
        int add = (t >= d) ? s[t - d] : 0;
        __syncthreads();
        s[t] += add;
        __syncthreads();
    }
    if (t < NBUCK) {
        int st = s[t] - v;
        bstart[t] = st;
        bcursor[t] = st;
    }
    if (t == 0) {
        bstart[NBUCK] = N_EDGES;
        rowptr[N_NODES] = N_EDGES;
    }
}

// ---------------- pass 1: partition edges into bucket regions -------------
__global__ __launch_bounds__(256) void k_bscatter(const int* __restrict__ src,
                                                  const int* __restrict__ tgt,
                                                  int* __restrict__ bcursor,
                                                  uint2* __restrict__ pairs) {
    __shared__ int h[NBUCK];
    __shared__ int rsv[NBUCK];
    for (int i = threadIdx.x; i < NBUCK; i += 256) h[i] = 0;
    __syncthreads();
    int i0 = blockIdx.x * CHUNK;
    int iend = i0 + CHUNK;
    if (iend > N_EDGES) iend = N_EDGES;
    for (int i = i0 + threadIdx.x; i < iend; i += 256)
        atomicAdd(&h[src[i] >> BSHIFT], 1);
    __syncthreads();
    for (int i = threadIdx.x; i < NBUCK; i += 256) {
        int c = h[i];
        rsv[i] = c ? atomicAdd(&bcursor[i], c) : 0;
        h[i] = 0;
    }
    __syncthreads();
    for (int i = i0 + threadIdx.x; i < iend; i += 256) {
        int s = src[i];
        int b = s >> BSHIFT;
        int p = rsv[b] + atomicAdd(&h[b], 1);
        pairs[p] = make_uint2((unsigned)s, (unsigned)tgt[i]);
    }
}

// ---------------- pass 2: in-bucket counting sort -> stgt + rowptr --------
__global__ __launch_bounds__(256) void k_bsort(const uint2* __restrict__ pairs,
                                               const int* __restrict__ bstart,
                                               int* __restrict__ rowptr,
                                               int* __restrict__ stgt) {
    __shared__ int h[128];
    __shared__ int s[128];
    int b = blockIdx.x;
    int p0 = bstart[b], p1 = bstart[b + 1];
    int n0 = b << BSHIFT;
    int t = threadIdx.x;
    if (t < 128) h[t] = 0;
    __syncthreads();
    for (int i = p0 + t; i < p1; i += 256)
        atomicAdd(&h[pairs[i].x & 127], 1);
    __syncthreads();
    int v = (t < 128) ? h[t] : 0;
    if (t < 128) s[t] = v;
    __syncthreads();
    for (int d = 1; d < 128; d <<= 1) {
        int add = (t >= d && t < 128) ? s[t - d] : 0;
        __syncthreads();
        if (t < 128) s[t] += add;
        __syncthreads();
    }
    if (t < 128) {
        int pos = p0 + s[t] - v;     // exclusive
        int node = n0 + t;
        if (node < N_NODES) rowptr[node] = pos;
        h[t] = pos;                  // running cursor (absolute)
    }
    __syncthreads();
    for (int i = p0 + t; i < p1; i += 256) {
        uint2 pr = pairs[i];
        int pos = atomicAdd(&h[pr.x & 127], 1);
        stgt[pos] = (int)pr.y;
    }
}

// ------- aggregate raw x rows with per-head softmax weights ---------------
__global__ __launch_bounds__(256) void k_agg(const int* __restrict__ rowptr,
                                             const int* __restrict__ stgt,
                                             const float* __restrict__ asrc,
                                             const float* __restrict__ atgt,
                                             const unsigned short* __restrict__ xb,
                                             unsigned short* __restrict__ agg) {
    int node = (blockIdx.x * 256 + threadIdx.x) >> 6;
    int lane = threadIdx.x & 63;
    if (node >= N_NODES) return;
    int base = rowptr[node], end = rowptr[node + 1];
    int h = lane >> 3, g = lane & 7;
    float a_s = asrc[node * 8 + h];
    float acc[16] = {};
    float den = 0.f;
    const unsigned short* __restrict__ xg = xb + g * 16;

    for (int c0 = base; c0 < end; c0 += 64) {
        int j = c0 + lane;
        int t = (j < end) ? stgt[j] : 0;
        int cnt = end - c0;
        if (cnt > 64) cnt = 64;
#pragma unroll 4
        for (int jj = 0; jj < cnt; ++jj) {
            int tj = __shfl(t, jj);
            ushort8 r0 = *reinterpret_cast<const ushort8*>(xg + (size_t)tj * 128);
            ushort8 r1 = *reinterpret_cast<const ushort8*>(xg + (size_t)tj * 128 + 8);
            float at = atgt[tj * 8 + h];
            float z = a_s + at;
            float e = (z > 0.f) ? -z : -(ALPHA * z);
            float w = __expf(e);
            den += w;
#pragma unroll
            for (int i = 0; i < 8; ++i) acc[i] = fmaf(w, b2f(r0[i]), acc[i]);
#pragma unroll
            for (int i = 0; i < 8; ++i) acc[8 + i] = fmaf(w, b2f(r1[i]), acc[8 + i]);
        }
    }
    float inv = 1.f / (den + 1e-10f);
    ushort8 o0, o1;
#pragma unroll
    for (int i = 0; i < 8; ++i) {
        o0[i] = f2b(acc[i] * inv);
        o1[i] = f2b(acc[8 + i] * inv);
    }
    unsigned short* op = agg + (size_t)node * 1024 + h * 128 + g * 16;
    *reinterpret_cast<ushort8*>(op) = o0;
    *reinterpret_cast<ushort8*>(op + 8) = o1;
}

// ------- final per-head GEMM: out[r][h*64+f] = agg[r][h][:] @ W[h][:][f] ---
#define LDK2 136
__global__ __launch_bounds__(256) void k_gemm2(const unsigned short* __restrict__ agg,
                                               const unsigned short* __restrict__ Wt,
                                               float* __restrict__ out) {
    __shared__ unsigned short Al[64 * LDK2];
    __shared__ unsigned short Bl[64 * LDK2];
    const int tid = threadIdx.x;
    const int h = blockIdx.y;
    const int r0 = blockIdx.x * 64;
    for (int it = 0; it < 4; ++it) {
        int idx = tid + it * 256;
        int r = idx >> 4, k8 = (idx & 15) << 3;
        int gr = r0 + r;
        if (gr >= N_NODES) gr = N_NODES - 1;
        *reinterpret_cast<ushort8*>(&Al[r * LDK2 + k8]) =
            *reinterpret_cast<const ushort8*>(agg + (size_t)gr * 1024 + h * 128 + k8);
    }
    for (int it = 0; it < 4; ++it) {
        int idx = tid + it * 256;
        int f = idx >> 4, k8 = (idx & 15) << 3;
        *reinterpret_cast<ushort8*>(&Bl[f * LDK2 + k8]) =
            *reinterpret_cast<const ushort8*>(Wt + (size_t)(h * 64 + f) * 128 + k8);
    }
    __syncthreads();
    const int lane = tid & 63, w = tid >> 6;
    const int l15 = lane & 15, lq = lane >> 4;
    f32x4 acc[4] = {};
    for (int ks = 0; ks < 4; ++ks) {
        int koff = ks * 32 + lq * 8;
        bf16x8 af = *reinterpret_cast<const bf16x8*>(&Al[(w * 16 + l15) * LDK2 + koff]);
#pragma unroll
        for (int n = 0; n < 4; ++n) {
            bf16x8 bf_ = *reinterpret_cast<const bf16x8*>(&Bl[(n * 16 + l15) * LDK2 + koff]);
            acc[n] = __builtin_amdgcn_mfma_f32_16x16x32_bf16(af, bf_, acc[n], 0, 0, 0);
        }
    }
    for (int n = 0; n < 4; ++n) {
        int col = h * 64 + n * 16 + l15;
        int rbase = r0 + w * 16 + lq * 4;
#pragma unroll
        for (int r2 = 0; r2 < 4; ++r2) {
            int rr = rbase + r2;
            if (rr < N_NODES) out[(size_t)rr * 512 + col] = acc[n][r2];
        }
    }
}

extern "C" void kernel_launch(void* const* d_in, const int* in_sizes, int n_in,
                              void* d_out, int out_size, void* d_ws, size_t ws_size,
                              hipStream_t stream) {
    const float* x = (const float*)d_in[0];
    const int* edges = (const int*)d_in[1];
    const float* W = (const float*)d_in[2];
    const float* a = (const float*)d_in[3];
    float* out = (float*)d_out;
    const int* src = edges;
    const int* tgt = edges + N_EDGES;

    char* ws = (char*)d_ws;
    size_t off = 0;
    auto alloc = [&](size_t bytes) -> void* {
        void* p = (void*)(ws + off);
        off += (bytes + 255) & ~(size_t)255;
        return p;
    };
    unsigned short* Wt = (unsigned short*)alloc((size_t)HEADS * OUT_F * IN_F * 2);
    float* u = (float*)alloc(HEADS * IN_F * 4);
    float* v = (float*)alloc(HEADS * IN_F * 4);
    unsigned short* xb = (unsigned short*)alloc((size_t)N_NODES * IN_F * 2);  // 25.6 MB
    float* asrc = (float*)alloc((size_t)N_NODES * 8 * 4);
    float* atgt = (float*)alloc((size_t)N_NODES * 8 * 4);
    int* bhist = (int*)alloc((size_t)NBUCK * 4);
    int* bstart = (int*)alloc((size_t)(NBUCK + 1) * 4);
    int* bcursor = (int*)alloc((size_t)NBUCK * 4);
    int* rowptr = (int*)alloc((size_t)(N_NODES + 1) * 4);
    uint2* pairs = (uint2*)alloc((size_t)N_EDGES * 8);   // 25.6 MB
    int* stgt = (int*)alloc((size_t)N_EDGES * 4);        // 12.8 MB
    (void)ws_size; (void)n_in; (void)in_sizes; (void)out_size;

    hipMemsetAsync(bhist, 0, (size_t)NBUCK * 4, stream);
    k_prep_w<<<256, 256, 0, stream>>>(W, Wt);
    k_uv<<<1, 1024, 0, stream>>>(W, a, u, v);
    k_xadot<<<25000, 256, 0, stream>>>(x, u, v, xb, asrc, atgt);
    k_bcount<<<NPBLK, 256, 0, stream>>>(src, bhist);
    k_bscan<<<1, 1024, 0, stream>>>(bhist, bstart, bcursor, rowptr);
    k_bscatter<<<NPBLK, 256, 0, stream>>>(src, tgt, bcursor, pairs);
    k_bsort<<<NBUCK, 256, 0, stream>>>(pairs, bstart, rowptr, stgt);
    k_agg<<<25000, 256, 0, stream>>>(rowptr, stgt, asrc, atgt, xb,
                                     (unsigned short*)d_out);
    k_gemm2<<<dim3(1563, 8), 256, 0, stream>>>((const unsigned short*)d_out, Wt, out);
}

// Round 8
// 556.935 us; speedup vs baseline: 3.3133x; 1.0639x over previous
//
#include <hip/hip_runtime.h>
#include <hip/hip_bf16.h>

#define N_NODES 100000
#define N_EDGES 3200000
#define IN_F 128
#define OUT_F 64
#define HEADS 8
#define ALPHA 0.2f

#define BSHIFT 7
#define NBUCK 782           // ceil(100000 / 128)
#define CHUNK 16384         // edges per partition block
#define NPBLK 196           // ceil(N_EDGES / CHUNK)

typedef __bf16 bf16x8 __attribute__((ext_vector_type(8)));
typedef float f32x4 __attribute__((ext_vector_type(4)));
typedef __attribute__((ext_vector_type(8))) unsigned short ushort8;

static __device__ __forceinline__ unsigned short f2b(float f) {
    __hip_bfloat16 h = __float2bfloat16(f);
    return __builtin_bit_cast(unsigned short, h);
}
static __device__ __forceinline__ float b2f(unsigned short u) {
    unsigned int x = ((unsigned int)u) << 16;
    return __builtin_bit_cast(float, x);
}

static __device__ __forceinline__ void gll16(const void* g, void* l) {
    __builtin_amdgcn_global_load_lds(
        (const __attribute__((address_space(1))) void*)g,
        (__attribute__((address_space(3))) void*)l, 16, 0, 0);
}

// ---------------- W transpose+convert: Wt[c=h*64+f][k] bf16 ----------------
__global__ void k_prep_w(const float* __restrict__ W, unsigned short* __restrict__ Wt) {
    int idx = blockIdx.x * 256 + threadIdx.x;
    if (idx >= HEADS * OUT_F * IN_F) return;
    int k = idx & 127;
    int c = idx >> 7;
    int h = c >> 6;
    int f = c & 63;
    Wt[idx] = f2b(W[h * IN_F * OUT_F + k * OUT_F + f]);
}

// ---------------- u[h][k] = sum_f W[h][k][f]*a[h][f]; v with a[h][64+f] ----
__global__ __launch_bounds__(1024) void k_uv(const float* __restrict__ W,
                                             const float* __restrict__ a,
                                             float* __restrict__ u, float* __restrict__ v) {
    int t = threadIdx.x;
    int h = t >> 7, k = t & 127;
    const float* Wrow = W + h * IN_F * OUT_F + k * OUT_F;
    const float* ah = a + h * 2 * OUT_F;
    float su = 0.f, sv = 0.f;
    for (int f = 0; f < OUT_F; ++f) {
        float wv = Wrow[f];
        su += wv * ah[f];
        sv += wv * ah[OUT_F + f];
    }
    u[t] = su;
    v[t] = sv;
}

// ------- fused: x -> bf16 copy, and logits asrc/atgt via u,v dots ----------
__global__ __launch_bounds__(256) void k_xadot(const float* __restrict__ x,
                                               const float* __restrict__ u,
                                               const float* __restrict__ v,
                                               unsigned short* __restrict__ xb,
                                               float* __restrict__ asrc,
                                               float* __restrict__ atgt) {
    int node = (blockIdx.x * 256 + threadIdx.x) >> 6;
    int lane = threadIdx.x & 63;
    if (node >= N_NODES) return;
    float2 xv = *reinterpret_cast<const float2*>(x + (size_t)node * 128 + 2 * lane);
    ushort2 pv = make_ushort2(f2b(xv.x), f2b(xv.y));
    *reinterpret_cast<ushort2*>(xb + (size_t)node * 128 + 2 * lane) = pv;
    for (int h = 0; h < 8; ++h) {
        float2 uu = *reinterpret_cast<const float2*>(u + h * 128 + 2 * lane);
        float2 vv = *reinterpret_cast<const float2*>(v + h * 128 + 2 * lane);
        float s1 = xv.x * uu.x + xv.y * uu.y;
        float s2 = xv.x * vv.x + xv.y * vv.y;
        for (int d = 1; d < 64; d <<= 1) {
            s1 += __shfl_xor(s1, d);
            s2 += __shfl_xor(s2, d);
        }
        if (lane == 0) {
            asrc[node * 8 + h] = s1;
            atgt[node * 8 + h] = s2;
        }
    }
}

// ---------------- pass 0: global bucket histogram (LDS-privatized) --------
__global__ __launch_bounds__(256) void k_bcount(const int* __restrict__ src,
                                                int* __restrict__ bhist) {
    __shared__ int h[NBUCK];
    for (int i = threadIdx.x; i < NBUCK; i += 256) h[i] = 0;
    __syncthreads();
    int i0 = blockIdx.x * CHUNK;
    int iend = i0 + CHUNK;
    if (iend > N_EDGES) iend = N_EDGES;
    for (int i = i0 + threadIdx.x; i < iend; i += 256)
        atomicAdd(&h[src[i] >> BSHIFT], 1);
    __syncthreads();
    for (int i = threadIdx.x; i < NBUCK; i += 256)
        if (h[i]) atomicAdd(&bhist[i], h[i]);
}

// ---------------- bucket scan (1 block); also init cursors ----------------
__global__ __launch_bounds__(1024) void k_bscan(const int* __restrict__ bhist,
                                                int* __restrict__ bstart,
                                                int* __restrict__ bcursor,
                                                int* __restrict__ rowptr) {
    __shared__ int s[1024];
    int t = threadIdx.x;
    int v = (t < NBUCK) ? bhist[t] : 0;
    s[t] = v;
    __syncthreads();
    for (int d = 1; d < 1024; d <<= 1) {
        int add = (t >= d) ? s[t - d] : 0;
        __syncthreads();
        s[t] += add;
        __syncthreads();
    }
    if (t < NBUCK) {
        int st = s[t] - v;
        bstart[t] = st;
        bcursor[t] = st;
    }
    if (t == 0) {
        bstart[NBUCK] = N_EDGES;
        rowptr[N_NODES] = N_EDGES;
    }
}

// ---------------- pass 1: partition edges into bucket regions -------------
__global__ __launch_bounds__(256) void k_bscatter(const int* __restrict__ src,
                                                  const int* __restrict__ tgt,
                                                  int* __restrict__ bcursor,
                                                  uint2* __restrict__ pairs) {
    __shared__ int h[NBUCK];
    __shared__ int rsv[NBUCK];
    for (int i = threadIdx.x; i < NBUCK; i += 256) h[i] = 0;
    __syncthreads();
    int i0 = blockIdx.x * CHUNK;
    int iend = i0 + CHUNK;
    if (iend > N_EDGES) iend = N_EDGES;
    for (int i = i0 + threadIdx.x; i < iend; i += 256)
        atomicAdd(&h[src[i] >> BSHIFT], 1);
    __syncthreads();
    for (int i = threadIdx.x; i < NBUCK; i += 256) {
        int c = h[i];
        rsv[i] = c ? atomicAdd(&bcursor[i], c) : 0;
        h[i] = 0;
    }
    __syncthreads();
    for (int i = i0 + threadIdx.x; i < iend; i += 256) {
        int s = src[i];
        int b = s >> BSHIFT;
        int p = rsv[b] + atomicAdd(&h[b], 1);
        pairs[p] = make_uint2((unsigned)s, (unsigned)tgt[i]);
    }
}

// ---------------- pass 2: in-bucket counting sort -> stgt + rowptr --------
__global__ __launch_bounds__(256) void k_bsort(const uint2* __restrict__ pairs,
                                               const int* __restrict__ bstart,
                                               int* __restrict__ rowptr,
                                               int* __restrict__ stgt) {
    __shared__ int h[128];
    __shared__ int s[128];
    int b = blockIdx.x;
    int p0 = bstart[b], p1 = bstart[b + 1];
    int n0 = b << BSHIFT;
    int t = threadIdx.x;
    if (t < 128) h[t] = 0;
    __syncthreads();
    for (int i = p0 + t; i < p1; i += 256)
        atomicAdd(&h[pairs[i].x & 127], 1);
    __syncthreads();
    int v = (t < 128) ? h[t] : 0;
    if (t < 128) s[t] = v;
    __syncthreads();
    for (int d = 1; d < 128; d <<= 1) {
        int add = (t >= d && t < 128) ? s[t - d] : 0;
        __syncthreads();
        if (t < 128) s[t] += add;
        __syncthreads();
    }
    if (t < 128) {
        int pos = p0 + s[t] - v;
        int node = n0 + t;
        if (node < N_NODES) rowptr[node] = pos;
        h[t] = pos;
    }
    __syncthreads();
    for (int i = p0 + t; i < p1; i += 256) {
        uint2 pr = pairs[i];
        int pos = atomicAdd(&h[pr.x & 127], 1);
        stgt[pos] = (int)pr.y;
    }
}

// ------- k_agg5: zero-duplication aggregation, LDS-staged -----------------
// One wave per node. Chunk = 16 edges. Per-wave LDS buf (x2 dbuf):
//   [0..1023]   : raw atgt rows, 32B per edge (lanes 32-63 mirror = pad)
//   [1024..5119]: X[e][seg]: 16 edges x 256B bf16 x-rows, linear
// Staged by 5x global_load_lds width-16 (per-lane global src, zero dup).
// Compute lane: hp = lane>>4 (heads 2hp,2hp+1), seg = lane&15 (8 feats).
// Per edge: 1 ds_read_b128 (x seg) + 1 ds_read_b64 (atgt pair) + 8 unpack
// + 16 fma. Denominators complete per-lane (no reduction).
#define AGG_CH 16
__global__ __launch_bounds__(256) void k_agg5(const int* __restrict__ rowptr,
                                              const int* __restrict__ stgt,
                                              const float* __restrict__ asrc,
                                              const float* __restrict__ atgt,
                                              const unsigned short* __restrict__ xb,
                                              unsigned short* __restrict__ aggout) {
    __shared__ char lds[4 * 2 * 5120];
    const int tid = threadIdx.x;
    const int wid = tid >> 6, lane = tid & 63;
    const int node = blockIdx.x * 4 + wid;
    if (node >= N_NODES) return;
    const int seg = lane & 15;
    const int hp = lane >> 4;
    const int base = rowptr[node], end = rowptr[node + 1];
    const float2 asr = *reinterpret_cast<const float2*>(asrc + (size_t)node * 8 + hp * 2);
    char* wbase = lds + wid * 10240;

    float accA[8] = {}, accB[8] = {};
    float denA = 0.f, denB = 0.f;

    const int deg = end - base;
    const int nch = (deg + AGG_CH - 1) >> 4;

    auto stage = [&](char* buf, int t16) {
        // atgt tile: e = (lane&31)>>1, half = lane&1
        int te_a = __shfl(t16, (lane & 31) >> 1);
        gll16(atgt + (size_t)te_a * 8 + (lane & 1) * 4, buf);
        // X tiles: 4 insts, each 4 edges; e = q*4 + (lane>>4), seg = lane&15
#pragma unroll
        for (int q = 0; q < 4; ++q) {
            int te = __shfl(t16, q * 4 + (lane >> 4));
            gll16(xb + (size_t)te * 128 + seg * 8, buf + 1024 + q * 1024);
        }
    };

    if (nch > 0) {
        int i0 = base + seg;
        if (i0 >= end) i0 = end - 1;
        int t16 = stgt[i0];
        stage(wbase, t16);
        if (nch > 1) {
            int i1 = base + 16 + seg;
            if (i1 >= end) i1 = end - 1;
            t16 = stgt[i1];
        }
        asm volatile("s_waitcnt vmcnt(0)" ::: "memory");
        int cur = 0;
        for (int c = 0; c < nch; ++c) {
            if (c + 1 < nch) {
                stage(wbase + (cur ^ 1) * 5120, t16);
                if (c + 2 < nch) {
                    int i2 = base + (c + 2) * 16 + seg;
                    if (i2 >= end) i2 = end - 1;
                    t16 = stgt[i2];
                }
            }
            const char* Xb = wbase + cur * 5120 + 1024;
            const char* Wb = wbase + cur * 5120;
            int c0 = base + c * 16;
            int cnt = end - c0;
            if (cnt > 16) cnt = 16;
#pragma unroll 4
            for (int e = 0; e < 16; ++e) {
                if (e >= cnt) break;
                ushort8 xv = *reinterpret_cast<const ushort8*>(Xb + e * 256 + seg * 16);
                float2 at = *reinterpret_cast<const float2*>(Wb + e * 32 + hp * 8);
                float z0 = asr.x + at.x, z1 = asr.y + at.y;
                float e0 = (z0 > 0.f) ? -z0 : -(ALPHA * z0);
                float e1 = (z1 > 0.f) ? -z1 : -(ALPHA * z1);
                float w0 = __expf(e0);
                float w1 = __expf(e1);
                denA += w0;
                denB += w1;
#pragma unroll
                for (int i = 0; i < 8; ++i) {
                    float xf = b2f(xv[i]);
                    accA[i] = fmaf(w0, xf, accA[i]);
                    accB[i] = fmaf(w1, xf, accB[i]);
                }
            }
            asm volatile("s_waitcnt vmcnt(0)" ::: "memory");
            cur ^= 1;
        }
    }

    float invA = 1.f / (denA + 1e-10f);
    float invB = 1.f / (denB + 1e-10f);
    ushort8 oA, oB;
#pragma unroll
    for (int i = 0; i < 8; ++i) {
        oA[i] = f2b(accA[i] * invA);
        oB[i] = f2b(accB[i] * invB);
    }
    unsigned short* op = aggout + (size_t)node * 1024 + (hp * 2) * 128 + seg * 8;
    *reinterpret_cast<ushort8*>(op) = oA;
    *reinterpret_cast<ushort8*>(op + 128) = oB;
}

// ------- final per-head GEMM: out[r][h*64+f] = agg[r][h][:] @ W[h][:][f] ---
#define LDK2 136
__global__ __launch_bounds__(256) void k_gemm2(const unsigned short* __restrict__ agg,
                                               const unsigned short* __restrict__ Wt,
                                               float* __restrict__ out) {
    __shared__ unsigned short Al[64 * LDK2];
    __shared__ unsigned short Bl[64 * LDK2];
    const int tid = threadIdx.x;
    const int h = blockIdx.y;
    const int r0 = blockIdx.x * 64;
    for (int it = 0; it < 4; ++it) {
        int idx = tid + it * 256;
        int r = idx >> 4, k8 = (idx & 15) << 3;
        int gr = r0 + r;
        if (gr >= N_NODES) gr = N_NODES - 1;
        *reinterpret_cast<ushort8*>(&Al[r * LDK2 + k8]) =
            *reinterpret_cast<const ushort8*>(agg + (size_t)gr * 1024 + h * 128 + k8);
    }
    for (int it = 0; it < 4; ++it) {
        int idx = tid + it * 256;
        int f = idx >> 4, k8 = (idx & 15) << 3;
        *reinterpret_cast<ushort8*>(&Bl[f * LDK2 + k8]) =
            *reinterpret_cast<const ushort8*>(Wt + (size_t)(h * 64 + f) * 128 + k8);
    }
    __syncthreads();
    const int lane = tid & 63, w = tid >> 6;
    const int l15 = lane & 15, lq = lane >> 4;
    f32x4 acc[4] = {};
    for (int ks = 0; ks < 4; ++ks) {
        int koff = ks * 32 + lq * 8;
        bf16x8 af = *reinterpret_cast<const bf16x8*>(&Al[(w * 16 + l15) * LDK2 + koff]);
#pragma unroll
        for (int n = 0; n < 4; ++n) {
            bf16x8 bf_ = *reinterpret_cast<const bf16x8*>(&Bl[(n * 16 + l15) * LDK2 + koff]);
            acc[n] = __builtin_amdgcn_mfma_f32_16x16x32_bf16(af, bf_, acc[n], 0, 0, 0);
        }
    }
    for (int n = 0; n < 4; ++n) {
        int col = h * 64 + n * 16 + l15;
        int rbase = r0 + w * 16 + lq * 4;
#pragma unroll
        for (int r2 = 0; r2 < 4; ++r2) {
            int rr = rbase + r2;
            if (rr < N_NODES) out[(size_t)rr * 512 + col] = acc[n][r2];
        }
    }
}

extern "C" void kernel_launch(void* const* d_in, const int* in_sizes, int n_in,
                              void* d_out, int out_size, void* d_ws, size_t ws_size,
                              hipStream_t stream) {
    const float* x = (const float*)d_in[0];
    const int* edges = (const int*)d_in[1];
    const float* W = (const float*)d_in[2];
    const float* a = (const float*)d_in[3];
    float* out = (float*)d_out;
    const int* src = edges;
    const int* tgt = edges + N_EDGES;

    char* ws = (char*)d_ws;
    size_t off = 0;
    auto alloc = [&](size_t bytes) -> void* {
        void* p = (void*)(ws + off);
        off += (bytes + 255) & ~(size_t)255;
        return p;
    };
    unsigned short* Wt = (unsigned short*)alloc((size_t)HEADS * OUT_F * IN_F * 2);
    float* u = (float*)alloc(HEADS * IN_F * 4);
    float* v = (float*)alloc(HEADS * IN_F * 4);
    unsigned short* xb = (unsigned short*)alloc((size_t)N_NODES * IN_F * 2);  // 25.6 MB
    float* asrc = (float*)alloc((size_t)N_NODES * 8 * 4);
    float* atgt = (float*)alloc((size_t)N_NODES * 8 * 4);
    int* bhist = (int*)alloc((size_t)NBUCK * 4);
    int* bstart = (int*)alloc((size_t)(NBUCK + 1) * 4);
    int* bcursor = (int*)alloc((size_t)NBUCK * 4);
    int* rowptr = (int*)alloc((size_t)(N_NODES + 1) * 4);
    uint2* pairs = (uint2*)alloc((size_t)N_EDGES * 8);   // 25.6 MB
    int* stgt = (int*)alloc((size_t)N_EDGES * 4);        // 12.8 MB
    (void)ws_size; (void)n_in; (void)in_sizes; (void)out_size;

    hipMemsetAsync(bhist, 0, (size_t)NBUCK * 4, stream);
    k_prep_w<<<256, 256, 0, stream>>>(W, Wt);
    k_uv<<<1, 1024, 0, stream>>>(W, a, u, v);
    k_xadot<<<25000, 256, 0, stream>>>(x, u, v, xb, asrc, atgt);
    k_bcount<<<NPBLK, 256, 0, stream>>>(src, bhist);
    k_bscan<<<1, 1024, 0, stream>>>(bhist, bstart, bcursor, rowptr);
    k_bscatter<<<NPBLK, 256, 0, stream>>>(src, tgt, bcursor, pairs);
    k_bsort<<<NBUCK, 256, 0, stream>>>(pairs, bstart, rowptr, stgt);
    k_agg5<<<25000, 256, 0, stream>>>(rowptr, stgt, asrc, atgt, xb,
                                      (unsigned short*)d_out);
    k_gemm2<<<dim3(1563, 8), 256, 0, stream>>>((const unsigned short*)d_out, Wt, out);
}

// Round 9
// 519.937 us; speedup vs baseline: 3.5490x; 1.0712x over previous
//
#include <hip/hip_runtime.h>
#include <hip/hip_bf16.h>

#define N_NODES 100000
#define N_EDGES 3200000
#define IN_F 128
#define OUT_F 64
#define HEADS 8
#define ALPHA 0.2f

#define BSHIFT 7
#define NBUCK 782           // ceil(100000 / 128)
#define CHUNK 16384         // edges per partition block
#define NPBLK 196           // ceil(N_EDGES / CHUNK)

typedef __bf16 bf16x8 __attribute__((ext_vector_type(8)));
typedef float f32x4 __attribute__((ext_vector_type(4)));
typedef __attribute__((ext_vector_type(8))) unsigned short ushort8;

static __device__ __forceinline__ unsigned short f2b(float f) {
    __hip_bfloat16 h = __float2bfloat16(f);
    return __builtin_bit_cast(unsigned short, h);
}
static __device__ __forceinline__ float b2f(unsigned short u) {
    unsigned int x = ((unsigned int)u) << 16;
    return __builtin_bit_cast(float, x);
}

static __device__ __forceinline__ void gll16(const void* g, void* l) {
    __builtin_amdgcn_global_load_lds(
        (const __attribute__((address_space(1))) void*)g,
        (__attribute__((address_space(3))) void*)l, 16, 0, 0);
}

// ---------------- W transpose+convert: Wt[c=h*64+f][k] bf16 ----------------
__global__ void k_prep_w(const float* __restrict__ W, unsigned short* __restrict__ Wt) {
    int idx = blockIdx.x * 256 + threadIdx.x;
    if (idx >= HEADS * OUT_F * IN_F) return;
    int k = idx & 127;
    int c = idx >> 7;
    int h = c >> 6;
    int f = c & 63;
    Wt[idx] = f2b(W[h * IN_F * OUT_F + k * OUT_F + f]);
}

// ---------------- u[h][k] = sum_f W[h][k][f]*a[h][f]; v with a[h][64+f] ----
__global__ __launch_bounds__(1024) void k_uv(const float* __restrict__ W,
                                             const float* __restrict__ a,
                                             float* __restrict__ u, float* __restrict__ v) {
    int t = threadIdx.x;
    int h = t >> 7, k = t & 127;
    const float* Wrow = W + h * IN_F * OUT_F + k * OUT_F;
    const float* ah = a + h * 2 * OUT_F;
    float su = 0.f, sv = 0.f;
    for (int f = 0; f < OUT_F; ++f) {
        float wv = Wrow[f];
        su += wv * ah[f];
        sv += wv * ah[OUT_F + f];
    }
    u[t] = su;
    v[t] = sv;
}

// ------- fused: x -> bf16 copy, and logits asrc/atgt via u,v dots ----------
__global__ __launch_bounds__(256) void k_xadot(const float* __restrict__ x,
                                               const float* __restrict__ u,
                                               const float* __restrict__ v,
                                               unsigned short* __restrict__ xb,
                                               float* __restrict__ asrc,
                                               float* __restrict__ atgt) {
    int node = (blockIdx.x * 256 + threadIdx.x) >> 6;
    int lane = threadIdx.x & 63;
    if (node >= N_NODES) return;
    float2 xv = *reinterpret_cast<const float2*>(x + (size_t)node * 128 + 2 * lane);
    ushort2 pv = make_ushort2(f2b(xv.x), f2b(xv.y));
    *reinterpret_cast<ushort2*>(xb + (size_t)node * 128 + 2 * lane) = pv;
    for (int h = 0; h < 8; ++h) {
        float2 uu = *reinterpret_cast<const float2*>(u + h * 128 + 2 * lane);
        float2 vv = *reinterpret_cast<const float2*>(v + h * 128 + 2 * lane);
        float s1 = xv.x * uu.x + xv.y * uu.y;
        float s2 = xv.x * vv.x + xv.y * vv.y;
        for (int d = 1; d < 64; d <<= 1) {
            s1 += __shfl_xor(s1, d);
            s2 += __shfl_xor(s2, d);
        }
        if (lane == 0) {
            asrc[node * 8 + h] = s1;
            atgt[node * 8 + h] = s2;
        }
    }
}

// ---------------- pass 0: global bucket histogram (LDS-privatized) --------
__global__ __launch_bounds__(256) void k_bcount(const int* __restrict__ src,
                                                int* __restrict__ bhist) {
    __shared__ int h[NBUCK];
    for (int i = threadIdx.x; i < NBUCK; i += 256) h[i] = 0;
    __syncthreads();
    int i0 = blockIdx.x * CHUNK;
    int iend = i0 + CHUNK;
    if (iend > N_EDGES) iend = N_EDGES;
    for (int i = i0 + threadIdx.x; i < iend; i += 256)
        atomicAdd(&h[src[i] >> BSHIFT], 1);
    __syncthreads();
    for (int i = threadIdx.x; i < NBUCK; i += 256)
        if (h[i]) atomicAdd(&bhist[i], h[i]);
}

// ---------------- bucket scan (1 block); also init cursors ----------------
__global__ __launch_bounds__(1024) void k_bscan(const int* __restrict__ bhist,
                                                int* __restrict__ bstart,
                                                int* __restrict__ bcursor,
                                                int* __restrict__ rowptr) {
    __shared__ int s[1024];
    int t = threadIdx.x;
    int v = (t < NBUCK) ? bhist[t] : 0;
    s[t] = v;
    __syncthreads();
    for (int d = 1; d < 1024; d <<= 1) {
        int add = (t >= d) ? s[t - d] : 0;
        __syncthreads();
        s[t] += add;
        __syncthreads();
    }
    if (t < NBUCK) {
        int st = s[t] - v;
        bstart[t] = st;
        bcursor[t] = st;
    }
    if (t == 0) {
        bstart[NBUCK] = N_EDGES;
        rowptr[N_NODES] = N_EDGES;
    }
}

// ---------------- pass 1: partition edges into bucket regions -------------
__global__ __launch_bounds__(256) void k_bscatter(const int* __restrict__ src,
                                                  const int* __restrict__ tgt,
                                                  int* __restrict__ bcursor,
                                                  uint2* __restrict__ pairs) {
    __shared__ int h[NBUCK];
    __shared__ int rsv[NBUCK];
    for (int i = threadIdx.x; i < NBUCK; i += 256) h[i] = 0;
    __syncthreads();
    int i0 = blockIdx.x * CHUNK;
    int iend = i0 + CHUNK;
    if (iend > N_EDGES) iend = N_EDGES;
    for (int i = i0 + threadIdx.x; i < iend; i += 256)
        atomicAdd(&h[src[i] >> BSHIFT], 1);
    __syncthreads();
    for (int i = threadIdx.x; i < NBUCK; i += 256) {
        int c = h[i];
        rsv[i] = c ? atomicAdd(&bcursor[i], c) : 0;
        h[i] = 0;
    }
    __syncthreads();
    for (int i = i0 + threadIdx.x; i < iend; i += 256) {
        int s = src[i];
        int b = s >> BSHIFT;
        int p = rsv[b] + atomicAdd(&h[b], 1);
        pairs[p] = make_uint2((unsigned)s, (unsigned)tgt[i]);
    }
}

// ---------------- pass 2: in-bucket counting sort -> stgt + rowptr --------
__global__ __launch_bounds__(256) void k_bsort(const uint2* __restrict__ pairs,
                                               const int* __restrict__ bstart,
                                               int* __restrict__ rowptr,
                                               int* __restrict__ stgt) {
    __shared__ int h[128];
    __shared__ int s[128];
    int b = blockIdx.x;
    int p0 = bstart[b], p1 = bstart[b + 1];
    int n0 = b << BSHIFT;
    int t = threadIdx.x;
    if (t < 128) h[t] = 0;
    __syncthreads();
    for (int i = p0 + t; i < p1; i += 256)
        atomicAdd(&h[pairs[i].x & 127], 1);
    __syncthreads();
    int v = (t < 128) ? h[t] : 0;
    if (t < 128) s[t] = v;
    __syncthreads();
    for (int d = 1; d < 128; d <<= 1) {
        int add = (t >= d && t < 128) ? s[t - d] : 0;
        __syncthreads();
        if (t < 128) s[t] += add;
        __syncthreads();
    }
    if (t < 128) {
        int pos = p0 + s[t] - v;
        int node = n0 + t;
        if (node < N_NODES) rowptr[node] = pos;
        h[t] = pos;
    }
    __syncthreads();
    for (int i = p0 + t; i < p1; i += 256) {
        uint2 pr = pairs[i];
        int pos = atomicAdd(&h[pr.x & 127], 1);
        stgt[pos] = (int)pr.y;
    }
}

// ------- k_agg6: chunk-hoisted weights + packed-f32 FMA aggregation -------
// One wave per node. Chunk = 16 edges. Per-wave LDS buf (x2 dbuf, 5120B):
//   [0..1023]   : atgt rows (32B/edge) -> overwritten in-place with weights
//   [1024..5119]: X[e][seg] 16 edges x 256B bf16 rows
// Weight phase (once/chunk): lane (e=lane&15, hp=lane>>4) computes the two
// weights for its (edge, head-pair) in place; den accumulates per-lane.
// Compute phase: lane (seg=lane&15, hp=lane>>4); per edge 1 ds_read_b128 +
// 1 broadcast ds_read_b64 + 8 unpack + 8 v_pk_fma_f32.
__global__ __launch_bounds__(256) void k_agg6(const int* __restrict__ rowptr,
                                              const int* __restrict__ stgt,
                                              const float* __restrict__ asrc,
                                              const float* __restrict__ atgt,
                                              const unsigned short* __restrict__ xb,
                                              unsigned short* __restrict__ aggout) {
    __shared__ char lds[4 * 2 * 5120];
    const int tid = threadIdx.x;
    const int wid = tid >> 6, lane = tid & 63;
    const int node = blockIdx.x * 4 + wid;
    if (node >= N_NODES) return;
    const int seg = lane & 15;
    const int hp = lane >> 4;
    const int base = rowptr[node], end = rowptr[node + 1];
    const float2 asr = *reinterpret_cast<const float2*>(asrc + (size_t)node * 8 + hp * 2);
    char* wbase = lds + wid * 10240;

    float2 accA[4] = {}, accB[4] = {};
    float den0 = 0.f, den1 = 0.f;

    const int deg = end - base;
    const int nch = (deg + 15) >> 4;

    auto stage = [&](char* buf, int t16) {
        int te_a = __shfl(t16, (lane & 31) >> 1);
        gll16(atgt + (size_t)te_a * 8 + (lane & 1) * 4, buf);
#pragma unroll
        for (int q = 0; q < 4; ++q) {
            int te = __shfl(t16, q * 4 + hp);
            gll16(xb + (size_t)te * 128 + seg * 8, buf + 1024 + q * 1024);
        }
    };

#define EDGE_STEP(E) { \
        uint4 xu = *reinterpret_cast<const uint4*>(Xb + (E) * 256 + seg * 16); \
        float2 w2 = *reinterpret_cast<const float2*>(buf + (E) * 32 + hp * 8); \
        float2 wA = {w2.x, w2.x}, wB = {w2.y, w2.y}; \
        _Pragma("unroll") \
        for (int i = 0; i < 4; ++i) { \
            unsigned int u = (&xu.x)[i]; \
            float2 xv; \
            xv.x = __builtin_bit_cast(float, u << 16); \
            xv.y = __builtin_bit_cast(float, u & 0xFFFF0000u); \
            asm("v_pk_fma_f32 %0, %1, %2, %0" : "+v"(accA[i]) : "v"(xv), "v"(wA)); \
            asm("v_pk_fma_f32 %0, %1, %2, %0" : "+v"(accB[i]) : "v"(xv), "v"(wB)); \
        } }

    if (nch > 0) {
        int i0 = base + seg;
        if (i0 >= end) i0 = end - 1;
        int t16 = stgt[i0];
        stage(wbase, t16);
        if (nch > 1) {
            int i1 = base + 16 + seg;
            if (i1 >= end) i1 = end - 1;
            t16 = stgt[i1];
        }
        asm volatile("s_waitcnt vmcnt(0)" ::: "memory");
        int cur = 0;
        for (int c = 0; c < nch; ++c) {
            if (c + 1 < nch) {
                stage(wbase + (cur ^ 1) * 5120, t16);
                if (c + 2 < nch) {
                    int i2 = base + (c + 2) * 16 + seg;
                    if (i2 >= end) i2 = end - 1;
                    t16 = stgt[i2];
                }
            }
            char* buf = wbase + cur * 5120;
            int c0 = base + c * 16;
            int cnt = end - c0;
            if (cnt > 16) cnt = 16;
            // ---- weight phase: lane (e=seg, hp) in-place over buf[0..511]
            {
                float2 at2 = *reinterpret_cast<const float2*>(buf + seg * 32 + hp * 8);
                float z0 = asr.x + at2.x, z1 = asr.y + at2.y;
                float e0 = (z0 > 0.f) ? -z0 : -(ALPHA * z0);
                float e1 = (z1 > 0.f) ? -z1 : -(ALPHA * z1);
                bool ok = seg < cnt;
                float w0 = ok ? __expf(e0) : 0.f;
                float w1 = ok ? __expf(e1) : 0.f;
                den0 += w0;
                den1 += w1;
                float2 wout = {w0, w1};
                *reinterpret_cast<float2*>(buf + seg * 32 + hp * 8) = wout;
            }
            asm volatile("s_waitcnt lgkmcnt(0)" ::: "memory");
            __builtin_amdgcn_sched_barrier(0);
            // ---- compute phase
            const char* Xb = buf + 1024;
            if (cnt == 16) {
#pragma unroll 4
                for (int e = 0; e < 16; ++e) EDGE_STEP(e)
            } else {
                for (int e = 0; e < cnt; ++e) EDGE_STEP(e)
            }
            asm volatile("s_waitcnt vmcnt(0)" ::: "memory");
            cur ^= 1;
        }
    }
#undef EDGE_STEP

    // ---- den: sum over the 16 edge-slots (lanes sharing hp)
    for (int d = 1; d <= 8; d <<= 1) {
        den0 += __shfl_xor(den0, d);
        den1 += __shfl_xor(den1, d);
    }
    float invA = 1.f / (den0 + 1e-10f);
    float invB = 1.f / (den1 + 1e-10f);
    ushort8 oA, oB;
#pragma unroll
    for (int i = 0; i < 4; ++i) {
        oA[2 * i] = f2b(accA[i].x * invA);
        oA[2 * i + 1] = f2b(accA[i].y * invA);
        oB[2 * i] = f2b(accB[i].x * invB);
        oB[2 * i + 1] = f2b(accB[i].y * invB);
    }
    unsigned short* op = aggout + (size_t)node * 1024 + (hp * 2) * 128 + seg * 8;
    *reinterpret_cast<ushort8*>(op) = oA;
    *reinterpret_cast<ushort8*>(op + 128) = oB;
}

// ------- final per-head GEMM: out[r][h*64+f] = agg[r][h][:] @ W[h][:][f] ---
#define LDK2 136
__global__ __launch_bounds__(256) void k_gemm2(const unsigned short* __restrict__ agg,
                                               const unsigned short* __restrict__ Wt,
                                               float* __restrict__ out) {
    __shared__ unsigned short Al[64 * LDK2];
    __shared__ unsigned short Bl[64 * LDK2];
    const int tid = threadIdx.x;
    const int h = blockIdx.y;
    const int r0 = blockIdx.x * 64;
    for (int it = 0; it < 4; ++it) {
        int idx = tid + it * 256;
        int r = idx >> 4, k8 = (idx & 15) << 3;
        int gr = r0 + r;
        if (gr >= N_NODES) gr = N_NODES - 1;
        *reinterpret_cast<ushort8*>(&Al[r * LDK2 + k8]) =
            *reinterpret_cast<const ushort8*>(agg + (size_t)gr * 1024 + h * 128 + k8);
    }
    for (int it = 0; it < 4; ++it) {
        int idx = tid + it * 256;
        int f = idx >> 4, k8 = (idx & 15) << 3;
        *reinterpret_cast<ushort8*>(&Bl[f * LDK2 + k8]) =
            *reinterpret_cast<const ushort8*>(Wt + (size_t)(h * 64 + f) * 128 + k8);
    }
    __syncthreads();
    const int lane = tid & 63, w = tid >> 6;
    const int l15 = lane & 15, lq = lane >> 4;
    f32x4 acc[4] = {};
    for (int ks = 0; ks < 4; ++ks) {
        int koff = ks * 32 + lq * 8;
        bf16x8 af = *reinterpret_cast<const bf16x8*>(&Al[(w * 16 + l15) * LDK2 + koff]);
#pragma unroll
        for (int n = 0; n < 4; ++n) {
            bf16x8 bf_ = *reinterpret_cast<const bf16x8*>(&Bl[(n * 16 + l15) * LDK2 + koff]);
            acc[n] = __builtin_amdgcn_mfma_f32_16x16x32_bf16(af, bf_, acc[n], 0, 0, 0);
        }
    }
    for (int n = 0; n < 4; ++n) {
        int col = h * 64 + n * 16 + l15;
        int rbase = r0 + w * 16 + lq * 4;
#pragma unroll
        for (int r2 = 0; r2 < 4; ++r2) {
            int rr = rbase + r2;
            if (rr < N_NODES) out[(size_t)rr * 512 + col] = acc[n][r2];
        }
    }
}

extern "C" void kernel_launch(void* const* d_in, const int* in_sizes, int n_in,
                              void* d_out, int out_size, void* d_ws, size_t ws_size,
                              hipStream_t stream) {
    const float* x = (const float*)d_in[0];
    const int* edges = (const int*)d_in[1];
    const float* W = (const float*)d_in[2];
    const float* a = (const float*)d_in[3];
    float* out = (float*)d_out;
    const int* src = edges;
    const int* tgt = edges + N_EDGES;

    char* ws = (char*)d_ws;
    size_t off = 0;
    auto alloc = [&](size_t bytes) -> void* {
        void* p = (void*)(ws + off);
        off += (bytes + 255) & ~(size_t)255;
        return p;
    };
    unsigned short* Wt = (unsigned short*)alloc((size_t)HEADS * OUT_F * IN_F * 2);
    float* u = (float*)alloc(HEADS * IN_F * 4);
    float* v = (float*)alloc(HEADS * IN_F * 4);
    unsigned short* xb = (unsigned short*)alloc((size_t)N_NODES * IN_F * 2);  // 25.6 MB
    float* asrc = (float*)alloc((size_t)N_NODES * 8 * 4);
    float* atgt = (float*)alloc((size_t)N_NODES * 8 * 4);
    int* bhist = (int*)alloc((size_t)NBUCK * 4);
    int* bstart = (int*)alloc((size_t)(NBUCK + 1) * 4);
    int* bcursor = (int*)alloc((size_t)NBUCK * 4);
    int* rowptr = (int*)alloc((size_t)(N_NODES + 1) * 4);
    uint2* pairs = (uint2*)alloc((size_t)N_EDGES * 8);   // 25.6 MB
    int* stgt = (int*)alloc((size_t)N_EDGES * 4);        // 12.8 MB
    (void)ws_size; (void)n_in; (void)in_sizes; (void)out_size;

    hipMemsetAsync(bhist, 0, (size_t)NBUCK * 4, stream);
    k_prep_w<<<256, 256, 0, stream>>>(W, Wt);
    k_uv<<<1, 1024, 0, stream>>>(W, a, u, v);
    k_xadot<<<25000, 256, 0, stream>>>(x, u, v, xb, asrc, atgt);
    k_bcount<<<NPBLK, 256, 0, stream>>>(src, bhist);
    k_bscan<<<1, 1024, 0, stream>>>(bhist, bstart, bcursor, rowptr);
    k_bscatter<<<NPBLK, 256, 0, stream>>>(src, tgt, bcursor, pairs);
    k_bsort<<<NBUCK, 256, 0, stream>>>(pairs, bstart, rowptr, stgt);
    k_agg6<<<25000, 256, 0, stream>>>(rowptr, stgt, asrc, atgt, xb,
                                      (unsigned short*)d_out);
    k_gemm2<<<dim3(1563, 8), 256, 0, stream>>>((const unsigned short*)d_out, Wt, out);
}